// Round 1
// baseline (687.746 us; speedup 1.0000x reference)
//
#include <hip/hip_runtime.h>
#include <math.h>

// Problem shape (from reference setup_inputs): B=4096, D=2048, C=1000, N=C+B=5096.
#define D_DIM 2048

// ---------------------------------------------------------------------------
// Virtual concat: supports = [W (C rows); z (B rows)], each row D_DIM floats.
// ---------------------------------------------------------------------------
__device__ __forceinline__ const float* support_row(int i, const float* __restrict__ W,
                                                    const float* __restrict__ z, int C) {
  return (i < C) ? (W + (size_t)i * D_DIM) : (z + (size_t)(i - C) * D_DIM);
}

// ---------------------------------------------------------------------------
// fp32 GEMM: Cmat[M,N] = A[M,K] @ B[N,K]^T  (B stored row-major as [N,K]).
// 64x64 tile, BK=32, 256 threads, 4x4 microtile per thread.
// CONCAT: A rows < nA1 come from A, rows >= nA1 from A2 (virtual support concat).
// ---------------------------------------------------------------------------
#define BM 64
#define BN 64
#define BK 32

template <bool CONCAT>
__global__ __launch_bounds__(256) void gemm_bt(const float* __restrict__ A,
                                               const float* __restrict__ A2, int nA1,
                                               const float* __restrict__ B,
                                               float* __restrict__ Cmat,
                                               int M, int N, int K) {
  // +4 pad keeps 16B alignment for float4 LDS reads (row = 68 floats = 272B = 17*16B)
  // and breaks the 64-stride bank pattern on transpose writes.
  __shared__ float As[BK][BM + 4];
  __shared__ float Bs[BK][BN + 4];

  const int tid = threadIdx.x;
  const int row0 = blockIdx.x * BM;
  const int col0 = blockIdx.y * BN;
  const int tm = tid & 15;   // 0..15 -> rows tm*4..tm*4+3
  const int tn = tid >> 4;   // 0..15 -> cols tn*4..tn*4+3

  float acc[4][4];
#pragma unroll
  for (int i = 0; i < 4; i++)
#pragma unroll
    for (int j = 0; j < 4; j++) acc[i][j] = 0.f;

  const int lrow = tid >> 3;        // 0..31
  const int lk = (tid & 7) * 4;     // 0,4,...,28

  for (int k0 = 0; k0 < K; k0 += BK) {
#pragma unroll
    for (int h = 0; h < 2; h++) {
      const int rr = lrow + h * 32;
      // A tile (transpose into k-major LDS)
      {
        const int r = row0 + rr;
        float4 v = make_float4(0.f, 0.f, 0.f, 0.f);
        if (r < M) {
          const float* ap;
          if (CONCAT)
            ap = (r < nA1) ? (A + (size_t)r * K) : (A2 + (size_t)(r - nA1) * K);
          else
            ap = A + (size_t)r * K;
          v = *(const float4*)(ap + k0 + lk);
        }
        As[lk + 0][rr] = v.x;
        As[lk + 1][rr] = v.y;
        As[lk + 2][rr] = v.z;
        As[lk + 3][rr] = v.w;
      }
      // B tile
      {
        const int c = col0 + rr;
        float4 w = make_float4(0.f, 0.f, 0.f, 0.f);
        if (c < N) w = *(const float4*)(B + (size_t)c * K + k0 + lk);
        Bs[lk + 0][rr] = w.x;
        Bs[lk + 1][rr] = w.y;
        Bs[lk + 2][rr] = w.z;
        Bs[lk + 3][rr] = w.w;
      }
    }
    __syncthreads();

#pragma unroll
    for (int kk = 0; kk < BK; kk++) {
      const float4 a4 = *(const float4*)&As[kk][tm * 4];
      const float4 b4 = *(const float4*)&Bs[kk][tn * 4];
      const float av[4] = {a4.x, a4.y, a4.z, a4.w};
      const float bv[4] = {b4.x, b4.y, b4.z, b4.w};
#pragma unroll
      for (int i = 0; i < 4; i++)
#pragma unroll
        for (int j = 0; j < 4; j++) acc[i][j] = fmaf(av[i], bv[j], acc[i][j]);
    }
    __syncthreads();
  }

#pragma unroll
  for (int i = 0; i < 4; i++) {
    const int r = row0 + tm * 4 + i;
    if (r >= M) continue;
#pragma unroll
    for (int j = 0; j < 4; j++) {
      const int c = col0 + tn * 4 + j;
      if (c < N) Cmat[(size_t)r * N + c] = acc[i][j];
    }
  }
}

// ---------------------------------------------------------------------------
// Per-row argmax (lowest index on ties, matching jnp.argmax) + entropy
// H = log(sum_e) - sum((l-m)*e)/sum_e  where e = exp(l - max).
// One block per row.
// ---------------------------------------------------------------------------
__global__ __launch_bounds__(256) void row_stats(const float* __restrict__ logits, int C,
                                                 float* __restrict__ ent,
                                                 int* __restrict__ yhat) {
  const int r = blockIdx.x;
  const float* row = logits + (size_t)r * C;
  const int t = threadIdx.x;

  __shared__ float sm[256];
  __shared__ int si[256];
  float m = -3.0e38f;
  int mi = 0x7fffffff;
  for (int c = t; c < C; c += 256) {
    const float v = row[c];
    if (v > m) { m = v; mi = c; }  // strided indices increase -> first hit = lowest index
  }
  sm[t] = m;
  si[t] = mi;
  __syncthreads();
  for (int s = 128; s > 0; s >>= 1) {
    if (t < s) {
      const float vo = sm[t + s];
      const int io = si[t + s];
      if (vo > sm[t] || (vo == sm[t] && io < si[t])) { sm[t] = vo; si[t] = io; }
    }
    __syncthreads();
  }
  const float mx = sm[0];
  const int amax = si[0];

  float s1 = 0.f, s2 = 0.f;
  for (int c = t; c < C; c += 256) {
    const float d = row[c] - mx;
    const float e = expf(d);
    s1 += e;
    s2 += d * e;
  }
  __shared__ float r1[256];
  __shared__ float r2[256];
  r1[t] = s1;
  r2[t] = s2;
  __syncthreads();
  for (int s = 128; s > 0; s >>= 1) {
    if (t < s) { r1[t] += r1[t + s]; r2[t] += r2[t + s]; }
    __syncthreads();
  }
  if (t == 0) {
    ent[r] = logf(r1[0]) - r2[0] / r1[0];
    yhat[r] = amax;
  }
}

// ---------------------------------------------------------------------------
// L2 norm of each support row. One block per support.
// ---------------------------------------------------------------------------
__global__ __launch_bounds__(256) void norms_kernel(const float* __restrict__ z,
                                                    const float* __restrict__ W, int C,
                                                    float* __restrict__ norms) {
  const int i = blockIdx.x;
  const float* row = support_row(i, W, z, C);
  const int t = threadIdx.x;
  float s = 0.f;
  for (int d = t; d < D_DIM; d += 256) {
    const float v = row[d];
    s = fmaf(v, v, s);
  }
  __shared__ float red[256];
  red[t] = s;
  __syncthreads();
  for (int k = 128; k > 0; k >>= 1) {
    if (t < k) red[t] += red[t + k];
    __syncthreads();
  }
  if (t == 0) norms[i] = sqrtf(red[0]);
}

__global__ void count_kernel(const int* __restrict__ yhat, int Nsup, int* __restrict__ counts) {
  const int i = blockIdx.x * 256 + threadIdx.x;
  if (i < Nsup) atomicAdd(&counts[yhat[i]], 1);
}

// Exclusive prefix sum over C (<=1024) class counts. Single block.
__global__ __launch_bounds__(1024) void prefix_kernel(const int* __restrict__ counts, int C,
                                                      int* __restrict__ offs) {
  __shared__ int tmp[1024];
  const int t = threadIdx.x;
  tmp[t] = (t < C) ? counts[t] : 0;
  __syncthreads();
  for (int d = 1; d < 1024; d <<= 1) {
    const int v = (t >= d) ? tmp[t - d] : 0;
    __syncthreads();
    tmp[t] += v;
    __syncthreads();
  }
  if (t < C) offs[t] = tmp[t] - counts[t];
}

__global__ void scatter_kernel(const int* __restrict__ yhat, int Nsup,
                               const int* __restrict__ offs, int* __restrict__ cursor,
                               int* __restrict__ classlist) {
  const int i = blockIdx.x * 256 + threadIdx.x;
  if (i < Nsup) {
    const int c = yhat[i];
    const int p = atomicAdd(&cursor[c], 1);
    classlist[offs[c] + p] = i;
  }
}

// Per class: mark selected supports. If count <= K all are selected (the common
// case: mean count ~5, K=100). Otherwise exact rank-based K-smallest-entropy
// selection with top_k tie semantics (ties -> lower support index).
__global__ __launch_bounds__(256) void select_kernel(const int* __restrict__ counts,
                                                     const int* __restrict__ offs,
                                                     const int* __restrict__ classlist,
                                                     const float* __restrict__ ent,
                                                     const int* __restrict__ Kp,
                                                     int* __restrict__ flags) {
  const int c = blockIdx.x;
  const int cnt = counts[c];
  const int off = offs[c];
  const int K = *Kp;
  if (cnt <= K) {
    for (int j = threadIdx.x; j < cnt; j += 256) flags[classlist[off + j]] = 1;
  } else {
    for (int j = threadIdx.x; j < cnt; j += 256) {
      const int si = classlist[off + j];
      const float ei = ent[si];
      int rank = 0;
      for (int l = 0; l < cnt; l++) {
        const int sl = classlist[off + l];
        const float el = ent[sl];
        if (el < ei || (el == ei && sl < si)) rank++;
      }
      flags[si] = (rank < K) ? 1 : 0;
    }
  }
}

// Per class: weights_c[c][d] = normalize_d( sum_{selected i in class c} support_i[d]/||support_i|| )
// One block per class; thread t owns dims t, t+256, ..., t+1792 (8 dims).
__global__ __launch_bounds__(256) void accum_kernel(const float* __restrict__ z,
                                                    const float* __restrict__ W, int C,
                                                    const int* __restrict__ counts,
                                                    const int* __restrict__ offs,
                                                    const int* __restrict__ classlist,
                                                    const int* __restrict__ flags,
                                                    const float* __restrict__ norms,
                                                    float* __restrict__ weights) {
  const int c = blockIdx.x;
  const int cnt = counts[c];
  const int off = offs[c];
  const int t = threadIdx.x;

  float acc[8];
#pragma unroll
  for (int r = 0; r < 8; r++) acc[r] = 0.f;

  for (int j = 0; j < cnt; j++) {
    const int si = classlist[off + j];
    if (!flags[si]) continue;
    const float* row = support_row(si, W, z, C);
    const float inv = 1.0f / fmaxf(norms[si], 1e-12f);
#pragma unroll
    for (int r = 0; r < 8; r++) acc[r] = fmaf(row[t + r * 256], inv, acc[r]);
  }

  float ss = 0.f;
#pragma unroll
  for (int r = 0; r < 8; r++) ss = fmaf(acc[r], acc[r], ss);
  __shared__ float red[256];
  red[t] = ss;
  __syncthreads();
  for (int k = 128; k > 0; k >>= 1) {
    if (t < k) red[t] += red[t + k];
    __syncthreads();
  }
  const float invn = 1.0f / fmaxf(sqrtf(red[0]), 1e-12f);
#pragma unroll
  for (int r = 0; r < 8; r++) weights[(size_t)c * D_DIM + t + r * 256] = acc[r] * invn;
}

// ---------------------------------------------------------------------------
// Launch
// ---------------------------------------------------------------------------
extern "C" void kernel_launch(void* const* d_in, const int* in_sizes, int n_in,
                              void* d_out, int out_size, void* d_ws, size_t ws_size,
                              hipStream_t stream) {
  const float* z = (const float*)d_in[0];
  const float* W = (const float*)d_in[1];
  const int* Kp = (const int*)d_in[2];

  const int D = D_DIM;
  const int B = in_sizes[0] / D;   // 4096
  const int C = in_sizes[1] / D;   // 1000
  const int Nsup = C + B;          // 5096

  char* ws = (char*)d_ws;
  size_t off = 0;
  auto alloc = [&](size_t bytes) -> void* {
    void* p = ws + off;
    off += (bytes + 255) & ~(size_t)255;
    return p;
  };

  float* logits    = (float*)alloc((size_t)Nsup * C * sizeof(float));  // ~20.4 MB
  float* weights   = (float*)alloc((size_t)C * D * sizeof(float));     // ~8.2 MB
  float* ent       = (float*)alloc((size_t)Nsup * sizeof(float));
  int*   yhat      = (int*)alloc((size_t)Nsup * sizeof(int));
  float* norms     = (float*)alloc((size_t)Nsup * sizeof(float));
  int*   counts    = (int*)alloc((size_t)C * sizeof(int));
  int*   offs      = (int*)alloc((size_t)C * sizeof(int));
  int*   cursor    = (int*)alloc((size_t)C * sizeof(int));
  int*   classlist = (int*)alloc((size_t)Nsup * sizeof(int));
  int*   flags     = (int*)alloc((size_t)Nsup * sizeof(int));
  (void)ws_size;

  hipMemsetAsync(counts, 0, (size_t)C * sizeof(int), stream);
  hipMemsetAsync(cursor, 0, (size_t)C * sizeof(int), stream);

  // 1) logits[Nsup, C] = [W; z] @ W^T   (fp32 — argmax must be exact)
  {
    dim3 grid((Nsup + BM - 1) / BM, (C + BN - 1) / BN);
    gemm_bt<true><<<grid, 256, 0, stream>>>(W, z, C, W, logits, Nsup, C, D);
  }
  // 2) per-row argmax + entropy
  row_stats<<<Nsup, 256, 0, stream>>>(logits, C, ent, yhat);
  // 3) support norms
  norms_kernel<<<Nsup, 256, 0, stream>>>(z, W, C, norms);
  // 4) class histogram -> offsets -> class-sorted index list
  count_kernel<<<(Nsup + 255) / 256, 256, 0, stream>>>(yhat, Nsup, counts);
  prefix_kernel<<<1, 1024, 0, stream>>>(counts, C, offs);
  scatter_kernel<<<(Nsup + 255) / 256, 256, 0, stream>>>(yhat, Nsup, offs, cursor, classlist);
  // 5) per-class top-K selection (no-op path when count <= K)
  select_kernel<<<C, 256, 0, stream>>>(counts, offs, classlist, ent, Kp, flags);
  // 6) class prototype accumulation + column normalize -> weights[C, D] (row per class)
  accum_kernel<<<C, 256, 0, stream>>>(z, W, C, counts, offs, classlist, flags, norms, weights);
  // 7) out[B, C] = z @ weights^T
  {
    dim3 grid((B + BM - 1) / BM, (C + BN - 1) / BN);
    gemm_bt<false><<<grid, 256, 0, stream>>>(z, nullptr, 0, weights, (float*)d_out, B, C, D);
  }
}

// Round 2
// 240.946 us; speedup vs baseline: 2.8544x; 2.8544x over previous
//
#include <hip/hip_runtime.h>
#include <math.h>

// Problem shape (from reference setup_inputs): B=4096, D=2048, C=1000, N=C+B=5096.
#define D_DIM 2048
#define GAP_TAU 0.02f   // per-logit |fp16_approx - fp32_exact| bound (>20 sigma)

typedef _Float16 f16;
typedef f16 f16x8 __attribute__((ext_vector_type(8)));
typedef float f32x4 __attribute__((ext_vector_type(4)));

// ---------------------------------------------------------------------------
// Virtual concat: supports = [W (C rows); z (B rows)], each row D_DIM floats.
// ---------------------------------------------------------------------------
__device__ __forceinline__ const float* support_row(int i, const float* __restrict__ W,
                                                    const float* __restrict__ z, int C) {
  return (i < C) ? (W + (size_t)i * D_DIM) : (z + (size_t)(i - C) * D_DIM);
}

// ---------------------------------------------------------------------------
// fp32 -> fp16 conversion, 8 elements/thread (n must be a multiple of 8).
// ---------------------------------------------------------------------------
__global__ __launch_bounds__(256) void f32_to_f16(const float* __restrict__ src,
                                                  f16* __restrict__ dst, int n) {
  const int i = (blockIdx.x * 256 + threadIdx.x) * 8;
  if (i >= n) return;
  const float4 a = *(const float4*)(src + i);
  const float4 b = *(const float4*)(src + i + 4);
  f16x8 v;
  v[0] = (f16)a.x; v[1] = (f16)a.y; v[2] = (f16)a.z; v[3] = (f16)a.w;
  v[4] = (f16)b.x; v[5] = (f16)b.y; v[6] = (f16)b.z; v[7] = (f16)b.w;
  *(f16x8*)(dst + i) = v;
}

// ---------------------------------------------------------------------------
// fp16 MFMA GEMM: Cmat[M,N] = A[M,K] @ B[N,K]^T, fp32 out.
// 128x64 tile, BK=32, 256 threads (4 waves, 2x2), each wave 64x32 = 4x2 MFMA
// tiles of 16x16x32. LDS tiles row-major with 16B-chunk XOR swizzle
// (chunk' = chunk ^ ((row>>1)&3)) -> 2-way bank aliasing on both ds_write_b128
// and ds_read_b128 (free on CDNA4).
// CONCAT: A rows < nA1 from A, rows >= nA1 from A2 (virtual support concat).
// ---------------------------------------------------------------------------
#define GBM 128
#define GBN 64
#define GBK 32

template <bool CONCAT>
__global__ __launch_bounds__(256) void gemm_f16(const f16* __restrict__ A,
                                                const f16* __restrict__ A2, int nA1,
                                                const f16* __restrict__ B,
                                                float* __restrict__ Cmat,
                                                int M, int N, int K) {
  __shared__ __align__(16) f16 As[GBM * GBK];  // [row][32] rows of 64B, swizzled chunks
  __shared__ __align__(16) f16 Bs[GBN * GBK];

  const int tid = threadIdx.x;
  const int row0 = blockIdx.x * GBM;
  const int col0 = blockIdx.y * GBN;
  const int wave = tid >> 6;
  const int lane = tid & 63;
  const int quad = lane >> 4;
  const int lr = lane & 15;
  const int wr = (wave >> 1) * 64;  // wave row origin in tile
  const int wc = (wave & 1) * 32;   // wave col origin in tile

  // ---- staging setup: A = 2 chunks/thread, B = 1 chunk/thread (16B chunks)
  const f16* agp[2];
  bool aok[2];
  int ast[2];
  f16x8 zero8 = {0, 0, 0, 0, 0, 0, 0, 0};
#pragma unroll
  for (int s = 0; s < 2; s++) {
    const int slot = s * 256 + tid;       // 0..511
    const int ar = slot >> 2;             // tile row 0..127
    const int cc = slot & 3;              // chunk within row (8 f16 each)
    const int grow = row0 + ar;
    aok[s] = grow < M;
    const int safe = aok[s] ? grow : 0;
    const f16* base;
    if (CONCAT)
      base = (safe < nA1) ? (A + (size_t)safe * K) : (A2 + (size_t)(safe - nA1) * K);
    else
      base = A + (size_t)safe * K;
    agp[s] = base + cc * 8;                                  // + k0 in loop
    ast[s] = (ar << 5) + ((cc ^ ((ar >> 1) & 3)) << 3);      // swizzled LDS elem offset
  }
  const int br = tid >> 2;
  const int bcc = tid & 3;
  const bool bok = (col0 + br) < N;
  const f16* bgp = B + (size_t)(bok ? (col0 + br) : 0) * K + bcc * 8;
  const int bst = (br << 5) + ((bcc ^ ((br >> 1) & 3)) << 3);

  // ---- fragment read offsets (elems); swizzle reduces to (lr>>1)&3
  const int fsw = (quad ^ ((lr >> 1) & 3)) << 3;
  int aoff[4], boff[2];
#pragma unroll
  for (int tm = 0; tm < 4; tm++) aoff[tm] = ((wr + tm * 16 + lr) << 5) + fsw;
#pragma unroll
  for (int tn = 0; tn < 2; tn++) boff[tn] = ((wc + tn * 16 + lr) << 5) + fsw;

  f32x4 zero4 = {0.f, 0.f, 0.f, 0.f};
  f32x4 acc[4][2];
#pragma unroll
  for (int i = 0; i < 4; i++)
#pragma unroll
    for (int j = 0; j < 2; j++) acc[i][j] = zero4;

  for (int k0 = 0; k0 < K; k0 += GBK) {
    // load (VGPR staging; overlaps with previous iteration's MFMA tail)
    f16x8 av0 = aok[0] ? *(const f16x8*)(agp[0] + k0) : zero8;
    f16x8 av1 = aok[1] ? *(const f16x8*)(agp[1] + k0) : zero8;
    f16x8 bv  = bok    ? *(const f16x8*)(bgp + k0)    : zero8;
    __syncthreads();  // previous iteration's LDS reads complete
    *(f16x8*)(As + ast[0]) = av0;
    *(f16x8*)(As + ast[1]) = av1;
    *(f16x8*)(Bs + bst)    = bv;
    __syncthreads();  // stores visible

    f16x8 af[4], bf[2];
#pragma unroll
    for (int tm = 0; tm < 4; tm++) af[tm] = *(const f16x8*)(As + aoff[tm]);
#pragma unroll
    for (int tn = 0; tn < 2; tn++) bf[tn] = *(const f16x8*)(Bs + boff[tn]);
#pragma unroll
    for (int tm = 0; tm < 4; tm++)
#pragma unroll
      for (int tn = 0; tn < 2; tn++)
        acc[tm][tn] = __builtin_amdgcn_mfma_f32_16x16x32_f16(af[tm], bf[tn], acc[tm][tn], 0, 0, 0);
  }

  // epilogue: C/D layout col=lane&15, row=quad*4+reg
#pragma unroll
  for (int tm = 0; tm < 4; tm++) {
#pragma unroll
    for (int reg = 0; reg < 4; reg++) {
      const int r = row0 + wr + tm * 16 + quad * 4 + reg;
      if (r >= M) continue;
#pragma unroll
      for (int tn = 0; tn < 2; tn++) {
        const int c = col0 + wc + tn * 16 + lr;
        if (c < N) Cmat[(size_t)r * N + c] = acc[tm][tn][reg];
      }
    }
  }
}

// ---------------------------------------------------------------------------
// Per-row argmax (lowest index on ties) + top-2 gap + entropy from the
// APPROXIMATE (fp16-GEMM) logits. Rows with gap <= 2*GAP_TAU are flagged
// for exact fp32 re-check. One block per row.
// ---------------------------------------------------------------------------
__global__ __launch_bounds__(256) void row_stats(const float* __restrict__ logits, int C,
                                                 float* __restrict__ ent,
                                                 int* __restrict__ yhat,
                                                 float* __restrict__ rowmax,
                                                 int* __restrict__ ambig) {
  const int r = blockIdx.x;
  const float* row = logits + (size_t)r * C;
  const int t = threadIdx.x;

  __shared__ float s1v[256];
  __shared__ int s1i[256];
  __shared__ float s2v[256];
  float m1 = -3.0e38f, m2 = -3.0e38f;
  int i1 = 0x7fffffff;
  for (int c = t; c < C; c += 256) {
    const float v = row[c];
    if (v > m1) { m2 = m1; m1 = v; i1 = c; }
    else if (v > m2) { m2 = v; }
    else if (v == m1) { m2 = v; }  // duplicate max -> gap 0
  }
  s1v[t] = m1; s1i[t] = i1; s2v[t] = m2;
  __syncthreads();
  for (int s = 128; s > 0; s >>= 1) {
    if (t < s) {
      const float b1 = s1v[t + s]; const int bi = s1i[t + s]; const float b2 = s2v[t + s];
      const float a1 = s1v[t];     const int ai = s1i[t];     const float a2 = s2v[t];
      if (b1 > a1)      { s1v[t] = b1; s1i[t] = bi; s2v[t] = fmaxf(a1, b2); }
      else if (b1 < a1) { /* keep a1 */              s2v[t] = fmaxf(b1, a2); }
      else              { s1i[t] = min(ai, bi);      s2v[t] = a1; }
    }
    __syncthreads();
  }
  const float mx = s1v[0];
  const int amax = s1i[0];
  const float gap = mx - s2v[0];

  float p1 = 0.f, p2 = 0.f;
  for (int c = t; c < C; c += 256) {
    const float d = row[c] - mx;
    const float e = expf(d);
    p1 += e;
    p2 += d * e;
  }
  __shared__ float r1[256];
  __shared__ float r2[256];
  r1[t] = p1; r2[t] = p2;
  __syncthreads();
  for (int s = 128; s > 0; s >>= 1) {
    if (t < s) { r1[t] += r1[t + s]; r2[t] += r2[t + s]; }
    __syncthreads();
  }
  if (t == 0) {
    ent[r] = logf(r1[0]) - r2[0] / r1[0];
    yhat[r] = amax;
    rowmax[r] = mx;
    ambig[r] = (gap <= 2.0f * GAP_TAU) ? 1 : 0;
  }
}

// ---------------------------------------------------------------------------
// Exact argmax fix for ambiguous rows: candidate classes are those with
// approx logit >= rowmax - 2*TAU (provably contains the true argmax);
// compute exact fp32 dots for candidates only, pick max (lowest index ties).
// One block per support row; unflagged rows exit immediately.
// ---------------------------------------------------------------------------
__global__ __launch_bounds__(256) void argmax_fix(const float* __restrict__ logits, int C,
                                                  const float* __restrict__ z,
                                                  const float* __restrict__ W,
                                                  const float* __restrict__ rowmax,
                                                  const int* __restrict__ ambig,
                                                  int* __restrict__ yhat) {
  const int r = blockIdx.x;
  if (!ambig[r]) return;
  const int t = threadIdx.x;
  const float* rowl = logits + (size_t)r * C;
  const float thresh = rowmax[r] - 2.0f * GAP_TAU;

  __shared__ int cand[64];
  __shared__ int ncand;
  __shared__ float red[256];
  if (t == 0) ncand = 0;
  __syncthreads();
  for (int c = t; c < C; c += 256) {
    if (rowl[c] >= thresh) {
      const int p = atomicAdd(&ncand, 1);
      if (p < 64) cand[p] = c;
    }
  }
  __syncthreads();
  const bool overflow = (ncand > 64);   // astronomically unlikely; exact fallback
  const int nc = overflow ? C : ncand;

  const float* rowa = support_row(r, W, z, C);
  float best = -3.0e38f;
  int bi = C;
  for (int j = 0; j < nc; j++) {
    const int c = overflow ? j : cand[j];
    const float* wrow = W + (size_t)c * D_DIM;
    float s = 0.f;
    for (int d = t; d < D_DIM; d += 256) s = fmaf(rowa[d], wrow[d], s);
    red[t] = s;
    __syncthreads();
    for (int k = 128; k > 0; k >>= 1) {
      if (t < k) red[t] += red[t + k];
      __syncthreads();
    }
    const float v = red[0];
    __syncthreads();
    if (v > best || (v == best && c < bi)) { best = v; bi = c; }
  }
  if (t == 0) yhat[r] = bi;
}

// ---------------------------------------------------------------------------
// L2 norm of each support row. One block per support.
// ---------------------------------------------------------------------------
__global__ __launch_bounds__(256) void norms_kernel(const float* __restrict__ z,
                                                    const float* __restrict__ W, int C,
                                                    float* __restrict__ norms) {
  const int i = blockIdx.x;
  const float* row = support_row(i, W, z, C);
  const int t = threadIdx.x;
  float s = 0.f;
  for (int d = t; d < D_DIM; d += 256) {
    const float v = row[d];
    s = fmaf(v, v, s);
  }
  __shared__ float red[256];
  red[t] = s;
  __syncthreads();
  for (int k = 128; k > 0; k >>= 1) {
    if (t < k) red[t] += red[t + k];
    __syncthreads();
  }
  if (t == 0) norms[i] = sqrtf(red[0]);
}

__global__ void count_kernel(const int* __restrict__ yhat, int Nsup, int* __restrict__ counts) {
  const int i = blockIdx.x * 256 + threadIdx.x;
  if (i < Nsup) atomicAdd(&counts[yhat[i]], 1);
}

// Exclusive prefix sum over C (<=1024) class counts. Single block.
__global__ __launch_bounds__(1024) void prefix_kernel(const int* __restrict__ counts, int C,
                                                      int* __restrict__ offs) {
  __shared__ int tmp[1024];
  const int t = threadIdx.x;
  tmp[t] = (t < C) ? counts[t] : 0;
  __syncthreads();
  for (int d = 1; d < 1024; d <<= 1) {
    const int v = (t >= d) ? tmp[t - d] : 0;
    __syncthreads();
    tmp[t] += v;
    __syncthreads();
  }
  if (t < C) offs[t] = tmp[t] - counts[t];
}

__global__ void scatter_kernel(const int* __restrict__ yhat, int Nsup,
                               const int* __restrict__ offs, int* __restrict__ cursor,
                               int* __restrict__ classlist) {
  const int i = blockIdx.x * 256 + threadIdx.x;
  if (i < Nsup) {
    const int c = yhat[i];
    const int p = atomicAdd(&cursor[c], 1);
    classlist[offs[c] + p] = i;
  }
}

// Per class: mark selected supports. If count <= K all are selected (the common
// case). Otherwise exact rank-based K-smallest-entropy selection.
__global__ __launch_bounds__(256) void select_kernel(const int* __restrict__ counts,
                                                     const int* __restrict__ offs,
                                                     const int* __restrict__ classlist,
                                                     const float* __restrict__ ent,
                                                     const int* __restrict__ Kp,
                                                     int* __restrict__ flags) {
  const int c = blockIdx.x;
  const int cnt = counts[c];
  const int off = offs[c];
  const int K = *Kp;
  if (cnt <= K) {
    for (int j = threadIdx.x; j < cnt; j += 256) flags[classlist[off + j]] = 1;
  } else {
    for (int j = threadIdx.x; j < cnt; j += 256) {
      const int si = classlist[off + j];
      const float ei = ent[si];
      int rank = 0;
      for (int l = 0; l < cnt; l++) {
        const int sl = classlist[off + l];
        const float el = ent[sl];
        if (el < ei || (el == ei && sl < si)) rank++;
      }
      flags[si] = (rank < K) ? 1 : 0;
    }
  }
}

// Per class: weights[c][d] = normalize_d( sum_{selected i in class c} support_i[d]/||support_i|| )
__global__ __launch_bounds__(256) void accum_kernel(const float* __restrict__ z,
                                                    const float* __restrict__ W, int C,
                                                    const int* __restrict__ counts,
                                                    const int* __restrict__ offs,
                                                    const int* __restrict__ classlist,
                                                    const int* __restrict__ flags,
                                                    const float* __restrict__ norms,
                                                    float* __restrict__ weights) {
  const int c = blockIdx.x;
  const int cnt = counts[c];
  const int off = offs[c];
  const int t = threadIdx.x;

  float acc[8];
#pragma unroll
  for (int r = 0; r < 8; r++) acc[r] = 0.f;

  for (int j = 0; j < cnt; j++) {
    const int si = classlist[off + j];
    if (!flags[si]) continue;
    const float* row = support_row(si, W, z, C);
    const float inv = 1.0f / fmaxf(norms[si], 1e-12f);
#pragma unroll
    for (int r = 0; r < 8; r++) acc[r] = fmaf(row[t + r * 256], inv, acc[r]);
  }

  float ss = 0.f;
#pragma unroll
  for (int r = 0; r < 8; r++) ss = fmaf(acc[r], acc[r], ss);
  __shared__ float red[256];
  red[t] = ss;
  __syncthreads();
  for (int k = 128; k > 0; k >>= 1) {
    if (t < k) red[t] += red[t + k];
    __syncthreads();
  }
  const float invn = 1.0f / fmaxf(sqrtf(red[0]), 1e-12f);
#pragma unroll
  for (int r = 0; r < 8; r++) weights[(size_t)c * D_DIM + t + r * 256] = acc[r] * invn;
}

// ---------------------------------------------------------------------------
// Launch
// ---------------------------------------------------------------------------
extern "C" void kernel_launch(void* const* d_in, const int* in_sizes, int n_in,
                              void* d_out, int out_size, void* d_ws, size_t ws_size,
                              hipStream_t stream) {
  const float* z = (const float*)d_in[0];
  const float* W = (const float*)d_in[1];
  const int* Kp = (const int*)d_in[2];

  const int D = D_DIM;
  const int B = in_sizes[0] / D;   // 4096
  const int C = in_sizes[1] / D;   // 1000
  const int Nsup = C + B;          // 5096

  char* ws = (char*)d_ws;
  size_t off = 0;
  auto alloc = [&](size_t bytes) -> void* {
    void* p = ws + off;
    off += (bytes + 255) & ~(size_t)255;
    return p;
  };

  float* logits    = (float*)alloc((size_t)Nsup * C * sizeof(float));  // ~20.4 MB
  float* weights   = (float*)alloc((size_t)C * D * sizeof(float));     // ~8.2 MB
  f16*   zh        = (f16*)alloc((size_t)B * D * sizeof(f16));         // ~16.8 MB
  f16*   Wh        = (f16*)alloc((size_t)C * D * sizeof(f16));         // ~4.1 MB
  f16*   wh        = (f16*)alloc((size_t)C * D * sizeof(f16));         // ~4.1 MB
  float* ent       = (float*)alloc((size_t)Nsup * sizeof(float));
  float* rowmax    = (float*)alloc((size_t)Nsup * sizeof(float));
  int*   ambig     = (int*)alloc((size_t)Nsup * sizeof(int));
  int*   yhat      = (int*)alloc((size_t)Nsup * sizeof(int));
  float* norms     = (float*)alloc((size_t)Nsup * sizeof(float));
  int*   counts    = (int*)alloc((size_t)C * sizeof(int));
  int*   offs      = (int*)alloc((size_t)C * sizeof(int));
  int*   cursor    = (int*)alloc((size_t)C * sizeof(int));
  int*   classlist = (int*)alloc((size_t)Nsup * sizeof(int));
  int*   flags     = (int*)alloc((size_t)Nsup * sizeof(int));
  (void)ws_size;

  hipMemsetAsync(counts, 0, (size_t)C * sizeof(int), stream);
  hipMemsetAsync(cursor, 0, (size_t)C * sizeof(int), stream);

  // 0) fp32 -> fp16 conversions for MFMA inputs
  f32_to_f16<<<(B * D) / (256 * 8), 256, 0, stream>>>(z, zh, B * D);
  f32_to_f16<<<(C * D) / (256 * 8), 256, 0, stream>>>(W, Wh, C * D);

  // 1) logits[Nsup, C] ~= [W; z] @ W^T  (fp16 MFMA, fp32 accumulate)
  {
    dim3 grid((Nsup + GBM - 1) / GBM, (C + GBN - 1) / GBN);
    gemm_f16<true><<<grid, 256, 0, stream>>>(Wh, zh, C, Wh, logits, Nsup, C, D);
  }
  // 2) per-row argmax + gap flag + entropy (from approx logits)
  row_stats<<<Nsup, 256, 0, stream>>>(logits, C, ent, yhat, rowmax, ambig);
  // 2b) exact fp32 argmax repair for ambiguous rows (candidate dots only)
  argmax_fix<<<Nsup, 256, 0, stream>>>(logits, C, z, W, rowmax, ambig, yhat);
  // 3) support norms (fp32 exact)
  norms_kernel<<<Nsup, 256, 0, stream>>>(z, W, C, norms);
  // 4) class histogram -> offsets -> class-sorted index list
  count_kernel<<<(Nsup + 255) / 256, 256, 0, stream>>>(yhat, Nsup, counts);
  prefix_kernel<<<1, 1024, 0, stream>>>(counts, C, offs);
  scatter_kernel<<<(Nsup + 255) / 256, 256, 0, stream>>>(yhat, Nsup, offs, cursor, classlist);
  // 5) per-class top-K selection (no-op path when count <= K)
  select_kernel<<<C, 256, 0, stream>>>(counts, offs, classlist, ent, Kp, flags);
  // 6) class prototype accumulation + normalize -> weights[C, D] (fp32 exact)
  accum_kernel<<<C, 256, 0, stream>>>(z, W, C, counts, offs, classlist, flags, norms, weights);
  // 6b) weights -> fp16
  f32_to_f16<<<(C * D) / (256 * 8), 256, 0, stream>>>(weights, wh, C * D);
  // 7) out[B, C] = z @ weights^T  (fp16 MFMA)
  {
    dim3 grid((B + GBM - 1) / GBM, (C + GBN - 1) / GBN);
    gemm_f16<false><<<grid, 256, 0, stream>>>(zh, nullptr, 0, wh, (float*)d_out, B, C, D);
  }
}